// Round 3
// baseline (989.819 us; speedup 1.0000x reference)
//
#include <hip/hip_runtime.h>

// ---------------------------------------------------------------------------
// AttentionLayer fused implementation for MI355X (gfx950)  -- Round 3
// D=H=1024, B=128, R=512, M=B*R=65536
//
// R3 key change: score GEMM restructured to a BARRIER-FREE K-loop.
// R2's dbuf failed because the compiler drains vmcnt(0) at every
// __syncthreads -- prefetch could never stay in flight across a step.
// Now: V is pre-converted to bf16 (vbf_k), and score2_k streams MFMA
// fragments straight from global memory into registers (A: 16B/lane
// contiguous; B: 16B/lane), double-buffered in registers with
// compile-time buffer indices. No LDS, no __syncthreads in the K-loop;
// the compiler emits fine-grained per-use vmcnt, loads stay in flight
// across K-steps (the AITER-style pipeline the guide points to).
// ---------------------------------------------------------------------------

typedef __bf16 bf16x8 __attribute__((ext_vector_type(8)));
typedef __bf16 bf16x4 __attribute__((ext_vector_type(4)));
typedef float floatx4 __attribute__((ext_vector_type(4)));

__device__ __forceinline__ float tanh_fast(float x) {
    x = fminf(10.0f, fmaxf(-10.0f, x));
    float e = exp2f(x * 2.885390081777927f);
    return (e - 1.0f) * __builtin_amdgcn_rcpf(e + 1.0f);
}

// ---------------- K0: V fp32 -> bf16 (128 MB ws) --------------------------
__global__ __launch_bounds__(256) void vbf_k(
    const float* __restrict__ V, __bf16* __restrict__ Vb) {
    size_t idx = ((size_t)blockIdx.x * 256 + threadIdx.x) * 8;
    float4 f0 = *reinterpret_cast<const float4*>(V + idx);
    float4 f1 = *reinterpret_cast<const float4*>(V + idx + 4);
    bf16x8 u;
    u[0] = (__bf16)f0.x; u[1] = (__bf16)f0.y;
    u[2] = (__bf16)f0.z; u[3] = (__bf16)f0.w;
    u[4] = (__bf16)f1.x; u[5] = (__bf16)f1.y;
    u[6] = (__bf16)f1.z; u[7] = (__bf16)f1.w;
    *reinterpret_cast<bf16x8*>(Vb + idx) = u;
}

// ---------------- K1: transpose + convert Wv -> WvT (bf16) ----------------
__global__ __launch_bounds__(256) void wvt_kernel(
    const float* __restrict__ Wv, __bf16* __restrict__ WvT) {
    __shared__ float tile[64][65];
    const int k0 = blockIdx.x * 64, n0 = blockIdx.y * 64;
    const int c = threadIdx.x & 63, r = threadIdx.x >> 6;
#pragma unroll
    for (int i = 0; i < 16; ++i)
        tile[r + i * 4][c] = Wv[(size_t)(k0 + r + i * 4) * 1024 + n0 + c];
    __syncthreads();
#pragma unroll
    for (int i = 0; i < 16; ++i)
        WvT[(size_t)(n0 + r + i * 4) * 1024 + k0 + c] =
            (__bf16)tile[c][r + i * 4];
}

// ---------------- small fp32 GEMM: C[128,1024] = act(A@W + b) -------------
__global__ __launch_bounds__(512) void small_gemm_k(
    const float* __restrict__ A0, const float* __restrict__ W0,
    const float* __restrict__ b0, float* __restrict__ C0, int act0,
    const float* __restrict__ A1, const float* __restrict__ W1,
    const float* __restrict__ b1, float* __restrict__ C1, int act1) {
    const float* A; const float* W; const float* bs; float* C; int act;
    if (blockIdx.z == 0) { A = A0; W = W0; bs = b0; C = C0; act = act0; }
    else                 { A = A1; W = W1; bs = b1; C = C1; act = act1; }
    __shared__ float red[3][8][128];
    const int tid = threadIdx.x;
    const int nl = tid & 127, kq = tid >> 7;
    const int n = blockIdx.x * 128 + nl;
    const int m0 = blockIdx.y * 8;
    const float* Ab = A + m0 * 1024;
    float acc[8] = {};
    const int kbeg = kq * 256, kend = kbeg + 256;
#pragma unroll 4
    for (int k = kbeg; k < kend; ++k) {
        float w = W[(size_t)k * 1024 + n];
#pragma unroll
        for (int mi = 0; mi < 8; ++mi)
            acc[mi] = fmaf(Ab[mi * 1024 + k], w, acc[mi]);
    }
    if (kq > 0) {
#pragma unroll
        for (int mi = 0; mi < 8; ++mi) red[kq - 1][mi][nl] = acc[mi];
    }
    __syncthreads();
    if (kq == 0) {
        float bias = bs[n];
#pragma unroll
        for (int mi = 0; mi < 8; ++mi) {
            float v = acc[mi] + red[0][mi][nl] + red[1][mi][nl] +
                      red[2][mi][nl] + bias;
            if (act == 1) v = fmaxf(v, 0.0f);
            else if (act == 2) v = tanh_fast(v);
            C[(size_t)(m0 + mi) * 1024 + n] = v;
        }
    }
}

// ---------------- K5: fused score GEMM, barrier-free register streaming ----
// Wave tile 128x64 (8 m-frags x 4 n-frags, 16x16x32 bf16 MFMA). Block = 4
// waves covering 256 n (A-loads shared across waves via L1). Grid: 512
// m-blocks x 4 n-blocks, XCD-swizzled so the 4 n-peers of an m-block are
// consecutive on one XCD (A from L2). K-loop: fragments stream global->reg,
// register double-buffer, NO LDS, NO __syncthreads -> no vmcnt(0) drains.
template <bool ABF16>
__global__ __launch_bounds__(256, 2) void score2_k(
    const void* __restrict__ Vv, const __bf16* __restrict__ WvT,
    const float* __restrict__ bv, const float* __restrict__ h_att,
    const float* __restrict__ Wal, float* __restrict__ scores) {
    const int tid = threadIdx.x;
    const int bidx = blockIdx.x;
    const int xcd = bidx & 7;
    const int i = bidx >> 3;
    const int nt = i & 3;          // n-block 0..3
    const int mloc = i >> 2;       // 0..63
    const int m0 = (xcd * 64 + mloc) * 128;
    const int wid = tid >> 6, lane = tid & 63;
    const int n0 = nt * 256 + wid * 64;
    const int lcol = lane & 15, quad = lane >> 4;

    floatx4 acc[8][4] = {};

    const int laneoff = lcol * 1024 + quad * 8;  // per-lane element offset
    const __bf16* Ab = (const __bf16*)Vv + (size_t)m0 * 1024 + laneoff;
    const float* Af = (const float*)Vv + (size_t)m0 * 1024 + laneoff;
    const __bf16* Bb = WvT + (size_t)n0 * 1024 + laneoff;

    bf16x8 a[2][8], b[2][4];

    auto loadstep = [&](int buf, int kk) {
        const int ke = kk * 32;
        if constexpr (ABF16) {
#pragma unroll
            for (int mi = 0; mi < 8; ++mi)
                a[buf][mi] = *reinterpret_cast<const bf16x8*>(
                    Ab + mi * 16384 + ke);
        } else {
#pragma unroll
            for (int mi = 0; mi < 8; ++mi) {
                const float* p = Af + mi * 16384 + ke;
                float4 f0 = *reinterpret_cast<const float4*>(p);
                float4 f1 = *reinterpret_cast<const float4*>(p + 4);
                bf16x8 u;
                u[0] = (__bf16)f0.x; u[1] = (__bf16)f0.y;
                u[2] = (__bf16)f0.z; u[3] = (__bf16)f0.w;
                u[4] = (__bf16)f1.x; u[5] = (__bf16)f1.y;
                u[6] = (__bf16)f1.z; u[7] = (__bf16)f1.w;
                a[buf][mi] = u;
            }
        }
#pragma unroll
        for (int ni = 0; ni < 4; ++ni)
            b[buf][ni] = *reinterpret_cast<const bf16x8*>(
                Bb + ni * 16384 + ke);
    };
    auto mfmastep = [&](int buf) {
#pragma unroll
        for (int mi = 0; mi < 8; ++mi)
#pragma unroll
            for (int ni = 0; ni < 4; ++ni)
                acc[mi][ni] = __builtin_amdgcn_mfma_f32_16x16x32_bf16(
                    a[buf][mi], b[buf][ni], acc[mi][ni], 0, 0, 0);
    };

    // software pipeline, all buffer indices compile-time constant
    loadstep(0, 0);
    for (int kk2 = 0; kk2 < 15; ++kk2) {
        loadstep(1, 2 * kk2 + 1);
        mfmastep(0);                 // step 2*kk2
        loadstep(0, 2 * kk2 + 2);
        mfmastep(1);                 // step 2*kk2+1
    }
    loadstep(1, 31);
    mfmastep(0);                     // step 30
    mfmastep(1);                     // step 31

    // ---- epilogue: fused score partials ----
    const int b_idx = m0 >> 9;
    float wal[4], hat[4], bvv[4];
#pragma unroll
    for (int ni = 0; ni < 4; ++ni) {
        int n = n0 + ni * 16 + lcol;
        wal[ni] = Wal[n];
        hat[ni] = h_att[b_idx * 1024 + n];
        bvv[ni] = bv[n];
    }
    float p[32];
#pragma unroll
    for (int mi = 0; mi < 8; ++mi) {
#pragma unroll
        for (int rg = 0; rg < 4; ++rg) {
            float s = 0.f;
#pragma unroll
            for (int ni = 0; ni < 4; ++ni) {
                float x = acc[mi][ni][rg] + bvv[ni];
                x = fmaxf(x, 0.f);
                s = fmaf(wal[ni], tanh_fast(x + hat[ni]), s);
            }
            p[mi * 4 + rg] = s;
        }
    }
#pragma unroll
    for (int off = 1; off < 16; off <<= 1) {
#pragma unroll
        for (int j = 0; j < 32; ++j) p[j] += __shfl_xor(p[j], off, 64);
    }
    if (lcol == 0) {
#pragma unroll
        for (int mi = 0; mi < 8; ++mi)
#pragma unroll
            for (int rg = 0; rg < 4; ++rg) {
                int row = m0 + mi * 16 + quad * 4 + rg;
                atomicAdd(&scores[b_idx * 513 + (row & 511)],
                          p[mi * 4 + rg]);
            }
    }
}

// ---------------- K6: scores[b][512] from s_att/h_att ---------------------
__global__ __launch_bounds__(256) void lastrow_k(
    const float* __restrict__ s_att, const float* __restrict__ h_att,
    const float* __restrict__ Wal, float* __restrict__ scores) {
    int b = blockIdx.x, tid = threadIdx.x;
    float s = 0.f;
    for (int h = tid; h < 1024; h += 256)
        s += Wal[h] * tanh_fast(s_att[b * 1024 + h] + h_att[b * 1024 + h]);
#pragma unroll
    for (int off = 32; off >= 1; off >>= 1) s += __shfl_xor(s, off, 64);
    __shared__ float red[4];
    if ((tid & 63) == 0) red[tid >> 6] = s;
    __syncthreads();
    if (tid == 0) scores[b * 513 + 512] = red[0] + red[1] + red[2] + red[3];
}

// ---------------- K7: softmax over 513 ------------------------------------
__global__ __launch_bounds__(256) void softmax_k(
    const float* __restrict__ scores, float* __restrict__ alpha) {
    int b = blockIdx.x, tid = threadIdx.x;
    const float* s = scores + b * 513;
    float v0 = s[tid];
    float v1 = s[tid + 256];
    float v2 = (tid == 0) ? s[512] : -1e30f;
    float m = fmaxf(v0, fmaxf(v1, v2));
#pragma unroll
    for (int off = 32; off >= 1; off >>= 1) m = fmaxf(m, __shfl_xor(m, off, 64));
    __shared__ float red[4];
    int w = tid >> 6;
    if ((tid & 63) == 0) red[w] = m;
    __syncthreads();
    m = fmaxf(fmaxf(red[0], red[1]), fmaxf(red[2], red[3]));
    const float L2E = 1.4426950408889634f;
    float e0 = exp2f((v0 - m) * L2E);
    float e1 = exp2f((v1 - m) * L2E);
    float e2 = (tid == 0) ? exp2f((v2 - m) * L2E) : 0.f;
    float sum = e0 + e1 + e2;
#pragma unroll
    for (int off = 32; off >= 1; off >>= 1) sum += __shfl_xor(sum, off, 64);
    __syncthreads();
    if ((tid & 63) == 0) red[w] = sum;
    __syncthreads();
    sum = red[0] + red[1] + red[2] + red[3];
    float inv = 1.0f / sum;
    float* a = alpha + b * 513;
    a[tid] = e0 * inv;
    a[tid + 256] = e1 * inv;
    if (tid == 0) a[512] = e2 * inv;
}

// ---------------- K8: context + h_proj ------------------------------------
template <bool VBF>
__global__ __launch_bounds__(256) void ctx2_k(
    const void* __restrict__ Vv, const float* __restrict__ alpha,
    const float* __restrict__ s_proj, const float* __restrict__ h_proj,
    float* __restrict__ ctxsum) {
    const int b = blockIdx.x, dq = blockIdx.y;
    const int tid = threadIdx.x;
    const int dl = tid & 63, rq = tid >> 6;
    __shared__ float sal[513];
    __shared__ float red[3][64][4];
    for (int i = tid; i < 513; i += 256) sal[i] = alpha[b * 513 + i];
    __syncthreads();
    const int d0 = dq * 256 + dl * 4;
    float a0 = 0, a1 = 0, a2 = 0, a3 = 0;
    if constexpr (VBF) {
        const __bf16* vp =
            (const __bf16*)Vv + ((size_t)b * 512 + rq * 128) * 1024 + d0;
#pragma unroll 8
        for (int r = 0; r < 128; ++r) {
            float al = sal[rq * 128 + r];
            bf16x4 vv =
                *reinterpret_cast<const bf16x4*>(vp + (size_t)r * 1024);
            a0 = fmaf(al, (float)vv[0], a0);
            a1 = fmaf(al, (float)vv[1], a1);
            a2 = fmaf(al, (float)vv[2], a2);
            a3 = fmaf(al, (float)vv[3], a3);
        }
    } else {
        const float* vp =
            (const float*)Vv + ((size_t)b * 512 + rq * 128) * 1024 + d0;
#pragma unroll 8
        for (int r = 0; r < 128; ++r) {
            float al = sal[rq * 128 + r];
            const float4 vv =
                *reinterpret_cast<const float4*>(vp + (size_t)r * 1024);
            a0 = fmaf(al, vv.x, a0); a1 = fmaf(al, vv.y, a1);
            a2 = fmaf(al, vv.z, a2); a3 = fmaf(al, vv.w, a3);
        }
    }
    if (rq > 0) {
        red[rq - 1][dl][0] = a0; red[rq - 1][dl][1] = a1;
        red[rq - 1][dl][2] = a2; red[rq - 1][dl][3] = a3;
    }
    __syncthreads();
    if (rq == 0) {
#pragma unroll
        for (int q = 0; q < 3; ++q) {
            a0 += red[q][dl][0]; a1 += red[q][dl][1];
            a2 += red[q][dl][2]; a3 += red[q][dl][3];
        }
        float4 sp = *reinterpret_cast<const float4*>(s_proj + b * 1024 + d0);
        float4 hp = *reinterpret_cast<const float4*>(h_proj + b * 1024 + d0);
        float aR = sal[512];
        float4 o;
        o.x = fmaf(aR, sp.x, a0) + hp.x;
        o.y = fmaf(aR, sp.y, a1) + hp.y;
        o.z = fmaf(aR, sp.z, a2) + hp.z;
        o.w = fmaf(aR, sp.w, a3) + hp.w;
        *reinterpret_cast<float4*>(ctxsum + b * 1024 + d0) = o;
    }
}

// ---------------------------------------------------------------------------
extern "C" void kernel_launch(void* const* d_in, const int* in_sizes, int n_in,
                              void* d_out, int out_size, void* d_ws,
                              size_t ws_size, hipStream_t stream) {
    const float* V   = (const float*)d_in[0];
    const float* s_t = (const float*)d_in[1];
    const float* h_t = (const float*)d_in[2];
    const float* Wv  = (const float*)d_in[3];
    const float* bv  = (const float*)d_in[4];
    const float* Wsp = (const float*)d_in[5];
    const float* bsp = (const float*)d_in[6];
    const float* Wsa = (const float*)d_in[7];
    const float* bsa = (const float*)d_in[8];
    const float* Whp = (const float*)d_in[9];
    const float* bhp = (const float*)d_in[10];
    const float* Wha = (const float*)d_in[11];
    const float* bha = (const float*)d_in[12];
    const float* Wal = (const float*)d_in[13];
    // d_in[14] = bal: softmax-invariant constant -> dropped
    const float* Wcp = (const float*)d_in[15];
    const float* bcp = (const float*)d_in[16];
    float* out = (float*)d_out;

    const size_t VBF_BYTES = 134217728ull;  // 65536*1024*2
    const size_t NEED_BIG = 139461632ull;   // Vbf + WvT + buffers
    const bool big = ws_size >= NEED_BIG;

    char* ws = (char*)d_ws;
    __bf16* Vbf; __bf16* WvT; char* base;
    if (big) {
        Vbf = (__bf16*)ws;
        base = ws + VBF_BYTES;              // WvT + small buffers after Vbf
    } else {
        Vbf = nullptr;
        base = ws;
    }
    WvT           = (__bf16*)(base);                 // 2 MB
    float* s_proj = (float*)(base + 2097152);        // 512 KB
    float* h_proj = (float*)(base + 2621440);        // 512 KB
    float* s_att  = (float*)(base + 3145728);        // 512 KB
    float* h_att  = (float*)(base + 3670016);        // 512 KB
    float* scores = (float*)(base + 4194304);        // 262656 B
    float* alpha  = (float*)(base + 4456960);        // 262656 B
    float* ctxsum = (float*)(base + 4719616);        // 512 KB

    if (big)
        hipLaunchKernelGGL(vbf_k, dim3(32768), dim3(256), 0, stream, V, Vbf);
    hipLaunchKernelGGL(wvt_kernel, dim3(16, 16), dim3(256), 0, stream, Wv, WvT);
    hipLaunchKernelGGL(small_gemm_k, dim3(8, 16, 2), dim3(512), 0, stream,
                       s_t, Wsp, bsp, s_proj, 1,
                       h_t, Whp, bhp, h_proj, 2);
    hipLaunchKernelGGL(small_gemm_k, dim3(8, 16, 2), dim3(512), 0, stream,
                       s_proj, Wsa, bsa, s_att, 0,
                       h_proj, Wha, bha, h_att, 0);
    (void)hipMemsetAsync(scores, 0, 128 * 513 * sizeof(float), stream);
    if (big)
        hipLaunchKernelGGL(score2_k<true>, dim3(2048), dim3(256), 0, stream,
                           (const void*)Vbf, WvT, bv, h_att, Wal, scores);
    else
        hipLaunchKernelGGL(score2_k<false>, dim3(2048), dim3(256), 0, stream,
                           (const void*)V, WvT, bv, h_att, Wal, scores);
    hipLaunchKernelGGL(lastrow_k, dim3(128), dim3(256), 0, stream,
                       s_att, h_att, Wal, scores);
    hipLaunchKernelGGL(softmax_k, dim3(128), dim3(256), 0, stream,
                       scores, alpha);
    if (big)
        hipLaunchKernelGGL(ctx2_k<true>, dim3(128, 4), dim3(256), 0, stream,
                           (const void*)Vbf, alpha, s_proj, h_proj, ctxsum);
    else
        hipLaunchKernelGGL(ctx2_k<false>, dim3(128, 4), dim3(256), 0, stream,
                           (const void*)V, alpha, s_proj, h_proj, ctxsum);
    hipLaunchKernelGGL(small_gemm_k, dim3(8, 16, 1), dim3(512), 0, stream,
                       ctxsum, Wcp, bcp, out, 2,
                       ctxsum, Wcp, bcp, out, 2);
}